// Round 9
// baseline (65.570 us; speedup 1.0000x reference)
//
#include <hip/hip_runtime.h>
#include <math.h>

#define WIN 16   // +/- phoneme-index window (rounds 1/5/6/8 verified)
#define FPW 8    // frames per wave
#define NW  4    // waves per block
#define FPB (FPW * NW)   // 32 frames per block
#define CH  8    // staged rows per buffer (double-buffered: 2 x 16 KB)

// Kernel 1: per-batch inclusive cumsum of durations (double precision scan),
// centers c[b,n] = cumsum(dur)[b,n] - 0.5*dur[b,n]   (verbatim)
__global__ void centers_kernel(const float* __restrict__ dur,
                               float* __restrict__ c, int N) {
    extern __shared__ double s[];
    int b = blockIdx.x;
    int n = threadIdx.x;
    float d = (n < N) ? dur[(size_t)b * N + n] : 0.0f;
    if (n < N) s[n] = (double)d;
    __syncthreads();
    for (int off = 1; off < N; off <<= 1) {
        double v = (n >= off && n < N) ? s[n - off] : 0.0;
        __syncthreads();
        if (n < N) s[n] += v;
        __syncthreads();
    }
    if (n < N) c[(size_t)b * N + n] = (float)(s[n] - 0.5 * (double)d);
}

// Kernel 2: block = 4 waves x 8 frames. Verbatim round-8 search/softmax and
// weight gather (full-wave shfls). Changes vs round 8 (both order/layout
// only, weights and fma order bit-identical):
//  - weights stay in registers; broadcast per-k via v_readlane (VALU, not
//    the LDS pipe) instead of an LDS table  => LDS reads per k halve.
//  - double-buffered rows with chunk c+1's DMA issued BEFORE chunk c's fma
//    loop => the barrier's vmcnt drain overlaps ~1024 cy of compute.
__global__ __launch_bounds__(256, 4) void upsample_dbuf(
    const float* __restrict__ x,    // [B,N,H]
    const int* __restrict__ lens,   // [B]
    const float* __restrict__ c,    // [B,N]
    float* __restrict__ out,        // [B,T,H]
    int B, int N, int H, int T) {
    __shared__ float rows[2][CH][512];     // 32 KB staged input rows (H=512)
    __shared__ int   bnd[2];               // block union window [n0, nEnd]

    int nwg = gridDim.x;
    int bid = blockIdx.x;
    if ((nwg & 7) == 0) {                  // XCD-bijective swizzle
        int cpx = nwg >> 3;
        bid = (bid & 7) * cpx + (bid >> 3);
    }
    int wave = threadIdx.x >> 6;
    int lane = threadIdx.x & 63;

    int tilesPerB = T / FPB;
    int b   = bid / tilesPerB;
    int t0b = (bid - b * tilesPerB) * FPB;
    int t0  = t0b + wave * FPW;            // this wave's first frame

    const float* cb = c + (size_t)b * N;
    int L = lens[b];
    if (L < 1) L = 1;
    if (L > N) L = N;

    float tf[FPW];
    #pragma unroll
    for (int f = 0; f < FPW; ++f) tf[f] = (float)(t0 + f);

    // ---- one ballot lower_bound pass serves all 8 frames ----
    int lo[FPW];
    #pragma unroll
    for (int f = 0; f < FPW; ++f) lo[f] = 0;
    for (int s = 0; s < N; s += 64) {
        int n = s + lane;
        float v = (n < N) ? cb[n] : 3.0e38f;
        bool inb = (n < L);
        #pragma unroll
        for (int f = 0; f < FPW; ++f)
            lo[f] += __popcll(__ballot(inb && (v < tf[f])));
    }

    // ---- per-frame window + softmax (verbatim numerics; lane k = w_k) ----
    int a[FPW], e[FPW];
    float w[FPW];
    #pragma unroll
    for (int f = 0; f < FPW; ++f) {
        int j = lo[f];
        if (j >= L) j = L - 1;
        float cj   = cb[j];
        float cjm1 = cb[(j > 0) ? (j - 1) : 0];
        if (j > 0 && (tf[f] - cjm1) < (cj - tf[f])) j--;
        int af = j - WIN; if (af < 0) af = 0;
        int ef = j + WIN; if (ef > L - 1) ef = L - 1;
        int K = ef - af + 1;
        float sc = -3.0e38f;
        if (lane < K) {
            float d = tf[f] - cb[af + lane];
            sc = -0.5f * d * d;
        }
        float m = sc;
        #pragma unroll
        for (int off = 32; off; off >>= 1) m = fmaxf(m, __shfl_xor(m, off));
        float ev = (lane < K) ? __expf(sc - m) : 0.0f;
        float sum = ev;
        #pragma unroll
        for (int off = 32; off; off >>= 1) sum += __shfl_xor(sum, off);
        a[f] = af; e[f] = ef;
        w[f] = ev / sum;                   // lanes >= K hold exactly 0.0f
    }

    // block union window: nearest-index monotone in t => [w0.a[0], w3.e[7]]
    if (wave == 0 && lane == 0) bnd[0] = a[0];
    if (wave == NW - 1 && lane == 0) bnd[1] = e[FPW - 1];
    __syncthreads();
    int n0   = bnd[0];
    int span = bnd[1] - n0 + 1;
    int nchunks = (span + CH - 1) / CH;

    const float* gbase = x + ((size_t)b * N + n0) * (size_t)H;

    // async stage of one chunk into buffer `buf` (linear dest == linear read)
    auto stage = [&](int cidx, int buf) {
        int kb = cidx * CH;
        int klen = span - kb; if (klen > CH) klen = CH;
        for (int r = wave; r < klen; r += NW) {
            const char* g = (const char*)(gbase + (size_t)(kb + r) * H);
            __builtin_amdgcn_global_load_lds(
                (const __attribute__((address_space(1))) void*)(g + lane * 16),
                (__attribute__((address_space(3))) void*)&rows[buf][r][0], 16, 0, 0);
            __builtin_amdgcn_global_load_lds(
                (const __attribute__((address_space(1))) void*)(g + 1024 + lane * 16),
                (__attribute__((address_space(3))) void*)&rows[buf][r][256], 16, 0, 0);
        }
    };

    float4 acc[FPW][2];
    #pragma unroll
    for (int f = 0; f < FPW; ++f) {
        acc[f][0] = make_float4(0.f, 0.f, 0.f, 0.f);
        acc[f][1] = make_float4(0.f, 0.f, 0.f, 0.f);
    }

    stage(0, 0);
    __syncthreads();                       // chunk 0 resident

    for (int cidx = 0; cidx < nchunks; ++cidx) {
        int kb = cidx * CH;
        int klen = span - kb; if (klen > CH) klen = CH;
        int cur = cidx & 1;

        // prefetch next chunk first: DMA overlaps this chunk's fma loop
        if (cidx + 1 < nchunks) stage(cidx + 1, cur ^ 1);

        // per-lane weights for union index kb+lane (full-wave shfls,
        // verbatim round-8 gather; stays in registers)
        int nn = kb + lane;
        float wv[FPW];
        #pragma unroll
        for (int f = 0; f < FPW; ++f) {
            unsigned q = (unsigned)(nn + n0 - a[f]);
            float g = __shfl(w[f], (int)(q & 63u));
            wv[f] = (q < 64u) ? g : 0.0f;
        }

        // fma from LDS, ascending k; weights broadcast via readlane (VALU)
        for (int k = 0; k < klen; ++k) {
            float wk[FPW];
            #pragma unroll
            for (int f = 0; f < FPW; ++f)
                wk[f] = __uint_as_float(
                    __builtin_amdgcn_readlane(__float_as_uint(wv[f]), k));
            const float4* row = (const float4*)rows[cur][k];
            float4 va = row[lane];
            float4 vb = row[64 + lane];
            #pragma unroll
            for (int f = 0; f < FPW; ++f) {
                acc[f][0].x = fmaf(wk[f], va.x, acc[f][0].x);
                acc[f][0].y = fmaf(wk[f], va.y, acc[f][0].y);
                acc[f][0].z = fmaf(wk[f], va.z, acc[f][0].z);
                acc[f][0].w = fmaf(wk[f], va.w, acc[f][0].w);
                acc[f][1].x = fmaf(wk[f], vb.x, acc[f][1].x);
                acc[f][1].y = fmaf(wk[f], vb.y, acc[f][1].y);
                acc[f][1].z = fmaf(wk[f], vb.z, acc[f][1].z);
                acc[f][1].w = fmaf(wk[f], vb.w, acc[f][1].w);
            }
        }
        __syncthreads();   // next chunk resident + cur buffer safe to reuse
    }

    // ---- store the wave's 8 frames ----
    float* obase = out + ((size_t)b * T + t0) * (size_t)H;
    #pragma unroll
    for (int f = 0; f < FPW; ++f) {
        float4* o = (float4*)(obase + (size_t)f * H);
        o[lane]      = acc[f][0];
        o[64 + lane] = acc[f][1];
    }
}

extern "C" void kernel_launch(void* const* d_in, const int* in_sizes, int n_in,
                              void* d_out, int out_size, void* d_ws, size_t ws_size,
                              hipStream_t stream) {
    const float* x    = (const float*)d_in[0];  // [B,N,H] f32
    const int*   lens = (const int*)d_in[1];    // [B] int
    const float* dur  = (const float*)d_in[2];  // [B,N] f32

    int B  = in_sizes[1];
    int BN = in_sizes[2];
    int N  = BN / B;
    int H  = in_sizes[0] / BN;
    int T  = out_size / (B * H);

    float* c = (float*)d_ws;  // B*N floats

    centers_kernel<<<B, N, N * sizeof(double), stream>>>(dur, c, N);

    int blocks = (B * T) / FPB;             // 32 frames per block
    upsample_dbuf<<<blocks, 256, 0, stream>>>(x, lens, c, (float*)d_out,
                                              B, N, H, T);
}